// Round 2
// baseline (40.237 us; speedup 1.0000x reference)
//
#include <hip/hip_runtime.h>

#define NIN 8
#define NMF 4
#define NBATCH 1024
#define NRULES 65536
#define NBT 16       // batch tiles of 64 (one per lane)
#define NSPLIT 256   // 64 hi-groups x 4 lo-quarters
// grid = NBT * NSPLIT = 4096 blocks of 64 threads (1 wave each)

// ws layout (floats):
//   part : [0, 256*1024)   part[sidx][b]
//   den  : [262144, 263168) den[b]
#define WS_PART 0
#define WS_DEN  262144

__global__ __launch_bounds__(64, 4) void anfis_main(
    const float* __restrict__ x, const float* __restrict__ mu,
    const float* __restrict__ sigma, const float* __restrict__ cw,
    const float* __restrict__ cb, float* __restrict__ part,
    float* __restrict__ den) {
  int bid = blockIdx.x;
  int btile = bid >> 8;      // 0..15
  int sidx  = bid & 255;     // 0..255
  int hi4   = sidx >> 2;     // 0..63 -> hi0 = hi4*4
  int wq    = sidx & 3;      // lo quarter -> lo0 = wq*64
  int lane  = threadIdx.x;   // 0..63
  int b = btile * 64 + lane;

  // this lane's batch inputs (two coalesced float4 loads)
  const float4* xv = (const float4*)(x + b * 8);
  float4 xa = xv[0], xb = xv[1];
  float xs[8] = {xa.x, xa.y, xa.z, xa.w, xb.x, xb.y, xb.z, xb.w};

  // memberships for this lane's batch: ms[i*4+q]
  float ms[32];
#pragma unroll
  for (int j = 0; j < 32; ++j) {
    int i = j >> 2;
    float t = fabsf(sigma[j]) + 1e-5f;       // sigma[j]: uniform -> s_load
    float r = __builtin_amdgcn_rcpf(t);
    float nv = -0.5f * r * r;                // -inv_two_var
    float d = xs[i] - mu[j];                 // mu[j]: uniform -> s_load
    ms[j] = __expf(d * d * nv);              // exp(-d^2 * inv_two_var)
  }

  // denominator: sum over all rules of separable product = prod of row sums
  if (sidx == 0) {
    float dn = 1.0f;
#pragma unroll
    for (int i = 0; i < 8; ++i)
      dn *= (ms[i * 4 + 0] + ms[i * 4 + 1] + ms[i * 4 + 2] + ms[i * 4 + 3]);
    den[b] = dn;
  }

  // hi-weights for the 4 his in this group; fold in the d4 (lo-quarter) factor
  int d0 = (hi4 >> 4) & 3, d1 = (hi4 >> 2) & 3, d2 = hi4 & 3;
  float basew = ms[d0] * ms[4 + d1] * ms[8 + d2] * ms[16 + wq];
  float W[4];
#pragma unroll
  for (int h = 0; h < 4; ++h) W[h] = basew * ms[12 + h];

  int hi0 = hi4 * 4;
  int lo0 = wq * 64;

  float num = 0.0f;
#pragma unroll 1
  for (int h = 0; h < 4; ++h) {
    const float* cwp = cw + (size_t)((hi0 + h) * 256 + lo0) * 8;  // uniform
    const float* cbp = cb + ((hi0 + h) * 256 + lo0);              // uniform
    float acc = 0.0f;
#pragma unroll 1
    for (int d5 = 0; d5 < 4; ++d5) {
      float p5 = ms[20 + d5];
#pragma unroll
      for (int d6 = 0; d6 < 4; ++d6) {
        float p6 = p5 * ms[24 + d6];
#pragma unroll
        for (int d7 = 0; d7 < 4; ++d7) {
          int l = d5 * 16 + d6 * 4 + d7;
          float w3 = p6 * ms[28 + d7];
          const float* c = cwp + l * 8;      // uniform -> s_load_dwordx8
          float dot = cbp[l];                // uniform -> s_load
          dot = fmaf(xs[0], c[0], dot);
          dot = fmaf(xs[1], c[1], dot);
          dot = fmaf(xs[2], c[2], dot);
          dot = fmaf(xs[3], c[3], dot);
          dot = fmaf(xs[4], c[4], dot);
          dot = fmaf(xs[5], c[5], dot);
          dot = fmaf(xs[6], c[6], dot);
          dot = fmaf(xs[7], c[7], dot);
          acc = fmaf(w3, dot, acc);
        }
      }
    }
    num = fmaf(W[h], acc, num);
  }

  // coalesced partial write: lanes are consecutive batches
  part[sidx * NBATCH + b] = num;
}

__global__ __launch_bounds__(256) void anfis_final(
    const float* __restrict__ part, const float* __restrict__ den,
    float* __restrict__ out) {
  // 16 blocks x 256 threads; block owns 64 batches, 4 chunks of 64 splits
  int lane = threadIdx.x & 63;
  int chunk = threadIdx.x >> 6;
  int b = blockIdx.x * 64 + lane;

  float s = 0.0f;
#pragma unroll 8
  for (int k = 0; k < 64; ++k)
    s += part[(chunk * 64 + k) * NBATCH + b];   // coalesced across lanes

  __shared__ float red[4][64];
  red[chunk][lane] = s;
  __syncthreads();
  if (threadIdx.x < 64) {
    int bb = blockIdx.x * 64 + threadIdx.x;
    float tot = red[0][threadIdx.x] + red[1][threadIdx.x] +
                red[2][threadIdx.x] + red[3][threadIdx.x];
    out[bb] = tot / (den[bb] + 1e-6f);
  }
}

extern "C" void kernel_launch(void* const* d_in, const int* in_sizes, int n_in,
                              void* d_out, int out_size, void* d_ws, size_t ws_size,
                              hipStream_t stream) {
  const float* x     = (const float*)d_in[0];
  const float* mu    = (const float*)d_in[1];
  const float* sigma = (const float*)d_in[2];
  const float* cw    = (const float*)d_in[3];
  const float* cb    = (const float*)d_in[4];
  float* ws   = (float*)d_ws;
  float* part = ws + WS_PART;
  float* den  = ws + WS_DEN;
  float* out  = (float*)d_out;

  anfis_main<<<NBT * NSPLIT, 64, 0, stream>>>(x, mu, sigma, cw, cb, part, den);
  anfis_final<<<NBT, 256, 0, stream>>>(part, den, out);
}

// Round 3
// 20.863 us; speedup vs baseline: 1.9287x; 1.9287x over previous
//
#include <hip/hip_runtime.h>

typedef _Float16 half2v __attribute__((ext_vector_type(2)));
typedef _Float16 half8v __attribute__((ext_vector_type(8)));
typedef float floatx4 __attribute__((ext_vector_type(4)));

#define NBATCH 1024
#define NKSTEP 2048      // 65536 rules / 32 per k-step
#define NKSPLIT 64       // k-splits; 32 ksteps per wave
#define NMTILE 32        // 1024 batches / 32 per wave (2 row-blocks of 16)

__device__ __forceinline__ float sel4f(float a0, float a1, float a2, float a3, int d) {
  float r = (d == 1) ? a1 : a0;
  r = (d == 2) ? a2 : r;
  r = (d == 3) ? a3 : r;
  return r;
}

// ---------------- prep: swizzle [cw | cb | 0-pad] into MFMA B-fragment order (f16)
// B[k][col], k = rule within kstep: klocal = (l>>4)*8 + e, col = l&15.
// linear layout: bfrag[kstep*64 + l][e]
__global__ __launch_bounds__(256) void anfis_prep(
    const float* __restrict__ cw, const float* __restrict__ cb,
    half8v* __restrict__ bfrag) {
  int t = blockIdx.x * 256 + threadIdx.x;   // 0..131071
  int kstep = t >> 6;
  int l = t & 63;
  int g = l >> 4, col = l & 15;
  int rbase = kstep * 32 + g * 8;
  half8v o;
#pragma unroll
  for (int e = 0; e < 8; ++e) {
    int r = rbase + e;
    float v = (col < 8) ? cw[r * 8 + col] : ((col == 8) ? cb[r] : 0.0f);
    o[e] = (_Float16)v;
  }
  bfrag[t] = o;
}

// ---------------- per-batch membership context (all static register indexing)
struct Ctx {
  float ms3[4], ms4[4];
  float m5a, m5b, pre012;
  half2v tab[4];   // (d6half u,e>>2-sel) x (d7 pairs)
};

__device__ __forceinline__ Ctx make_ctx(const float* __restrict__ x,
                                        const float* __restrict__ mu,
                                        const float* __restrict__ sigma,
                                        int b, int d0, int d1, int d2,
                                        int u, int h) {
  float4 xlo = ((const float4*)(x + b * 8))[0];
  float4 xhi = ((const float4*)(x + b * 8))[1];
  float xs[8] = {xlo.x, xlo.y, xlo.z, xlo.w, xhi.x, xhi.y, xhi.z, xhi.w};
  float msD[8][4];
#pragma unroll
  for (int i = 0; i < 8; ++i)
#pragma unroll
    for (int q = 0; q < 4; ++q) {
      float s = fabsf(sigma[i * 4 + q]) + 1e-5f;     // uniform -> s_load
      float rs = __builtin_amdgcn_rcpf(s);
      float nv = -0.5f * rs * rs;
      float d = xs[i] - mu[i * 4 + q];               // uniform -> s_load
      msD[i][q] = __expf(d * d * nv);
    }
  Ctx c;
#pragma unroll
  for (int q = 0; q < 4; ++q) { c.ms3[q] = msD[3][q]; c.ms4[q] = msD[4][q]; }
  c.m5a = h ? msD[5][1] : msD[5][0];
  c.m5b = h ? msD[5][3] : msD[5][2];
  c.pre012 = sel4f(msD[0][0], msD[0][1], msD[0][2], msD[0][3], d0) *
             sel4f(msD[1][0], msD[1][1], msD[1][2], msD[1][3], d1) *
             sel4f(msD[2][0], msD[2][1], msD[2][2], msD[2][3], d2);
  float m6_0 = u ? msD[6][2] : msD[6][0];
  float m6_1 = u ? msD[6][3] : msD[6][1];
  c.tab[0] = (half2v){(_Float16)(m6_0 * msD[7][0]), (_Float16)(m6_0 * msD[7][1])};
  c.tab[1] = (half2v){(_Float16)(m6_0 * msD[7][2]), (_Float16)(m6_0 * msD[7][3])};
  c.tab[2] = (half2v){(_Float16)(m6_1 * msD[7][0]), (_Float16)(m6_1 * msD[7][1])};
  c.tab[3] = (half2v){(_Float16)(m6_1 * msD[7][2]), (_Float16)(m6_1 * msD[7][3])};
  return c;
}

// ---------------- main: W(generated) x Bfrag GEMM, 1 wave = 32 batches x 1024 rules
__global__ __launch_bounds__(64, 2) void anfis_main(
    const float* __restrict__ x, const float* __restrict__ mu,
    const float* __restrict__ sigma, const half8v* __restrict__ bfrag,
    float* __restrict__ part) {
  int bid = blockIdx.x;
  int mtile = bid >> 6;        // 0..31
  int ksplit = bid & 63;       // 0..63
  int l = threadIdx.x;
  int g = l >> 4, col = l & 15;
  int b0 = mtile * 32;
  int ks0 = ksplit * 32;

  int d2 = ksplit & 3, d1 = (ksplit >> 2) & 3, d0 = (ksplit >> 4) & 3;
  int u = g & 1, h = g >> 1;

  const half8v* Bp = bfrag + (size_t)ks0 * 64 + l;

  half8v bf[2][8];
#pragma unroll
  for (int jj = 0; jj < 8; ++jj) bf[0][jj] = Bp[jj * 64];   // prefetch group 0

  Ctx c0 = make_ctx(x, mu, sigma, b0 + (l & 15), d0, d1, d2, u, h);
  Ctx c1 = make_ctx(x, mu, sigma, b0 + 16 + (l & 15), d0, d1, d2, u, h);

  floatx4 acc0 = {0.f, 0.f, 0.f, 0.f}, acc1 = {0.f, 0.f, 0.f, 0.f};

#pragma unroll
  for (int j3 = 0; j3 < 4; ++j3) {        // d3 = j3
    if (j3 < 3) {
#pragma unroll
      for (int jj = 0; jj < 8; ++jj)
        bf[(j3 + 1) & 1][jj] = Bp[((j3 + 1) * 8 + jj) * 64];
    }
    float p3_0 = c0.pre012 * c0.ms3[j3];
    float p3_1 = c1.pre012 * c1.ms3[j3];
#pragma unroll
    for (int j4 = 0; j4 < 4; ++j4) {      // d4 = j4
      float p4_0 = p3_0 * c0.ms4[j4];
      float p4_1 = p3_1 * c1.ms4[j4];
#pragma unroll
      for (int j01 = 0; j01 < 2; ++j01) { // d5 = 2*j01 + h
        half8v b8 = bf[j3 & 1][j4 * 2 + j01];
        float p5_0 = p4_0 * (j01 ? c0.m5b : c0.m5a);
        _Float16 ph0 = (_Float16)p5_0;
        half2v pp0 = {ph0, ph0};
        half2v a00 = pp0 * c0.tab[0], a01 = pp0 * c0.tab[1],
               a02 = pp0 * c0.tab[2], a03 = pp0 * c0.tab[3];
        half8v a8_0 = {a00.x, a00.y, a01.x, a01.y, a02.x, a02.y, a03.x, a03.y};
        acc0 = __builtin_amdgcn_mfma_f32_16x16x32_f16(a8_0, b8, acc0, 0, 0, 0);
        float p5_1 = p4_1 * (j01 ? c1.m5b : c1.m5a);
        _Float16 ph1 = (_Float16)p5_1;
        half2v pp1 = {ph1, ph1};
        half2v a10 = pp1 * c1.tab[0], a11 = pp1 * c1.tab[1],
               a12 = pp1 * c1.tab[2], a13 = pp1 * c1.tab[3];
        half8v a8_1 = {a10.x, a10.y, a11.x, a11.y, a12.x, a12.y, a13.x, a13.y};
        acc1 = __builtin_amdgcn_mfma_f32_16x16x32_f16(a8_1, b8, acc1, 0, 0, 0);
      }
    }
  }

  // epilogue: fold x into C (C layout: col = l&15, row = (l>>4)*4 + i), cols 9..15 are 0
#pragma unroll
  for (int rb = 0; rb < 2; ++rb) {
    floatx4 acc = rb ? acc1 : acc0;
#pragma unroll
    for (int i = 0; i < 4; ++i) {
      int bb = b0 + rb * 16 + (l >> 4) * 4 + i;
      float xc = (col < 8) ? x[bb * 8 + col] : ((col == 8) ? 1.0f : 0.0f);
      float v = acc[i] * xc;
      v += __shfl_xor(v, 1);
      v += __shfl_xor(v, 2);
      v += __shfl_xor(v, 4);
      v += __shfl_xor(v, 8);
      if (col == 0) part[ksplit * NBATCH + bb] = v;
    }
  }
}

// ---------------- final: reduce k-splits + analytic separable denominator
__global__ __launch_bounds__(256) void anfis_final(
    const float* __restrict__ part, const float* __restrict__ x,
    const float* __restrict__ mu, const float* __restrict__ sigma,
    float* __restrict__ out) {
  int b = blockIdx.x * 256 + threadIdx.x;
  float s = 0.0f;
#pragma unroll
  for (int ks = 0; ks < NKSPLIT; ++ks) s += part[ks * NBATCH + b];
  float4 xlo = ((const float4*)(x + b * 8))[0];
  float4 xhi = ((const float4*)(x + b * 8))[1];
  float xs[8] = {xlo.x, xlo.y, xlo.z, xlo.w, xhi.x, xhi.y, xhi.z, xhi.w};
  float den = 1.0f;
#pragma unroll
  for (int i = 0; i < 8; ++i) {
    float rowsum = 0.0f;
#pragma unroll
    for (int q = 0; q < 4; ++q) {
      float sg = fabsf(sigma[i * 4 + q]) + 1e-5f;
      float rs = __builtin_amdgcn_rcpf(sg);
      float nv = -0.5f * rs * rs;
      float d = xs[i] - mu[i * 4 + q];
      rowsum += __expf(d * d * nv);
    }
    den *= rowsum;
  }
  out[b] = s / (den + 1e-6f);
}

extern "C" void kernel_launch(void* const* d_in, const int* in_sizes, int n_in,
                              void* d_out, int out_size, void* d_ws, size_t ws_size,
                              hipStream_t stream) {
  const float* x     = (const float*)d_in[0];
  const float* mu    = (const float*)d_in[1];
  const float* sigma = (const float*)d_in[2];
  const float* cw    = (const float*)d_in[3];
  const float* cb    = (const float*)d_in[4];
  half8v* bfrag = (half8v*)d_ws;                                   // 2 MB
  float* part = (float*)((char*)d_ws + (size_t)NKSTEP * 64 * 16);  // 256 KB
  float* out = (float*)d_out;

  anfis_prep<<<NKSTEP * 64 / 256, 256, 0, stream>>>(cw, cb, bfrag);
  anfis_main<<<NMTILE * NKSPLIT, 64, 0, stream>>>(x, mu, sigma, bfrag, part);
  anfis_final<<<NBATCH / 256, 256, 0, stream>>>(part, x, mu, sigma, out);
}